// Round 1
// 866.852 us; speedup vs baseline: 1.0962x; 1.0962x over previous
//
#include <hip/hip_runtime.h>

#define NN 2
#define CC 32
#define NCC 4
#define DD 96
#define WW 96
#define HH 96
#define PP (DD*WW*HH)          // 884736
#define NCP (NN*NCC*PP)        // 7077888
#define SD (WW*HH)             // 9216
#define SW HH                  // 96
#define EPS 1e-5f
#define BIGF 1e30f

__device__ __forceinline__ float wave_reduce(float v) {
#pragma unroll
    for (int off = 32; off > 0; off >>= 1) v += __shfl_down(v, off, 64);
    return v;
}

__device__ __forceinline__ float dot8(float4 a0, float4 a1, float4 b0, float4 b1) {
    return a0.x*b0.x + a0.y*b0.y + a0.z*b0.z + a0.w*b0.w
         + a1.x*b1.x + a1.y*b1.y + a1.z*b1.z + a1.w*b1.w;
}

__device__ __forceinline__ float sigf(float v) { return 1.f / (1.f + __expf(-v)); }

// ---- K1: fused sigmoid + 1-D pool along H. Thread owns 4 consecutive h.
//      mask=sigmoid(x); omax=maxH(mask); omin=minH(mask). ----
__global__ __launch_bounds__(256) void k_poolH(const float* __restrict__ x,
                                               float* __restrict__ mask,
                                               float* __restrict__ omax,
                                               float* __restrict__ omin) {
    int i = (blockIdx.x * 256 + threadIdx.x) * 4;
    int h0 = i % HH;                       // multiple of 4
    float4 xv = *(const float4*)(x + i);
    float v0 = sigf(xv.x), v1 = sigf(xv.y), v2 = sigf(xv.z), v3 = sigf(xv.w);
    float aM = -BIGF, bM = -BIGF, cM = -BIGF, dM = -BIGF;
    float am =  BIGF, bm =  BIGF, cm =  BIGF, dm =  BIGF;
    if (h0 > 0) {
        float t0 = sigf(x[i-2]), t1 = sigf(x[i-1]);
        aM = t0; am = t0; bM = t1; bm = t1;
    }
    if (h0 < 92) {
        float t0 = sigf(x[i+4]), t1 = sigf(x[i+5]);
        cM = t0; cm = t0; dM = t1; dm = t1;
    }
    float4 mo, mx, mn;
    mo.x = v0; mo.y = v1; mo.z = v2; mo.w = v3;
    mx.x = fmaxf(fmaxf(aM, bM), fmaxf(fmaxf(v0, v1), v2));
    mx.y = fmaxf(bM, fmaxf(fmaxf(v0, v1), fmaxf(v2, v3)));
    mx.z = fmaxf(fmaxf(fmaxf(v0, v1), fmaxf(v2, v3)), cM);
    mx.w = fmaxf(fmaxf(v1, v2), fmaxf(v3, fmaxf(cM, dM)));
    mn.x = fminf(fminf(am, bm), fminf(fminf(v0, v1), v2));
    mn.y = fminf(bm, fminf(fminf(v0, v1), fminf(v2, v3)));
    mn.z = fminf(fminf(fminf(v0, v1), fminf(v2, v3)), cm);
    mn.w = fminf(fminf(v1, v2), fminf(v3, fminf(cm, dm)));
    *(float4*)(mask + i) = mo;
    *(float4*)(omax + i) = mx;
    *(float4*)(omin + i) = mn;
}

// ---- K2: pool along W. omax = maxW(tmax); iomin = min(iomin, minW(mask)). ----
__global__ __launch_bounds__(256) void k_poolW(const float* __restrict__ tmax,
                                               const float* __restrict__ m,
                                               float* __restrict__ omax,
                                               float* __restrict__ iomin) {
    int i = (blockIdx.x * 256 + threadIdx.x) * 4;
    int w = (i / HH) % WW;
    float4 mx = make_float4(-BIGF, -BIGF, -BIGF, -BIGF);
    float4 mn = make_float4( BIGF,  BIGF,  BIGF,  BIGF);
#pragma unroll
    for (int dw = -2; dw <= 2; ++dw) {
        int wi = w + dw;
        if (wi >= 0 && wi < WW) {
            float4 a = *(const float4*)(tmax + i + dw*SW);
            float4 b = *(const float4*)(m + i + dw*SW);
            mx.x = fmaxf(mx.x, a.x); mx.y = fmaxf(mx.y, a.y);
            mx.z = fmaxf(mx.z, a.z); mx.w = fmaxf(mx.w, a.w);
            mn.x = fminf(mn.x, b.x); mn.y = fminf(mn.y, b.y);
            mn.z = fminf(mn.z, b.z); mn.w = fminf(mn.w, b.w);
        }
    }
    float4 prev = *(const float4*)(iomin + i);
    prev.x = fminf(prev.x, mn.x); prev.y = fminf(prev.y, mn.y);
    prev.z = fminf(prev.z, mn.z); prev.w = fminf(prev.w, mn.w);
    *(float4*)(omax + i) = mx;
    *(float4*)(iomin + i) = prev;
}

// ---- K3: pool along D. dil = maxD(tmax); ero = min(min12, minD(mask));
//      accumulates esum/dsum per (n,k). Block = 1024 contiguous elems. ----
__global__ __launch_bounds__(256) void k_poolD(const float* __restrict__ tmax,
                                               const float* __restrict__ m,
                                               const float* __restrict__ min12,
                                               float* __restrict__ dil,
                                               float* __restrict__ ero,
                                               float* __restrict__ esum,
                                               float* __restrict__ dsum) {
    int base = blockIdx.x * 1024;
    int nk = base / PP;
    int i = base + threadIdx.x * 4;
    int d = (i / SD) % DD;
    float4 mx = make_float4(-BIGF, -BIGF, -BIGF, -BIGF);
    float4 mn = make_float4( BIGF,  BIGF,  BIGF,  BIGF);
#pragma unroll
    for (int dd = -2; dd <= 2; ++dd) {
        int di = d + dd;
        if (di >= 0 && di < DD) {
            float4 a = *(const float4*)(tmax + i + dd*SD);
            float4 b = *(const float4*)(m + i + dd*SD);
            mx.x = fmaxf(mx.x, a.x); mx.y = fmaxf(mx.y, a.y);
            mx.z = fmaxf(mx.z, a.z); mx.w = fmaxf(mx.w, a.w);
            mn.x = fminf(mn.x, b.x); mn.y = fminf(mn.y, b.y);
            mn.z = fminf(mn.z, b.z); mn.w = fminf(mn.w, b.w);
        }
    }
    float4 m12 = *(const float4*)(min12 + i);
    float4 ev;
    ev.x = fminf(m12.x, mn.x); ev.y = fminf(m12.y, mn.y);
    ev.z = fminf(m12.z, mn.z); ev.w = fminf(m12.w, mn.w);
    *(float4*)(dil + i) = mx;
    *(float4*)(ero + i) = ev;
    float ae = ev.x + ev.y + ev.z + ev.w;
    float ad = mx.x + mx.y + mx.z + mx.w;
    ae = wave_reduce(ae); ad = wave_reduce(ad);
    __shared__ float se, sdv;
    if (threadIdx.x == 0) { se = 0.f; sdv = 0.f; }
    __syncthreads();
    if ((threadIdx.x & 63) == 0) { atomicAdd(&se, ae); atomicAdd(&sdv, ad); }
    __syncthreads();
    if (threadIdx.x == 0) { atomicAdd(&esum[nk], se); atomicAdd(&dsum[nk], sdv); }
}

// ---- K4: split-K dots. Per (n,c): dot_e[k], dot_d[k], fsum. ----
__global__ __launch_bounds__(256, 2) void k_dots(const float* __restrict__ feat,
                                                 const float* __restrict__ ero,
                                                 const float* __restrict__ dil,
                                                 float* __restrict__ dot_e,
                                                 float* __restrict__ dot_d,
                                                 float* __restrict__ fsum) {
    const int chunks_per_n = PP / 2048;   // 432
    int b = blockIdx.x;
    int n = b / chunks_per_n;
    int p0 = (b % chunks_per_n) * 2048 + threadIdx.x * 8;

    float4 e[NCC][2], dv[NCC][2];
#pragma unroll
    for (int k = 0; k < NCC; ++k) {
        const float* pe = ero + ((size_t)(n*NCC + k))*PP + p0;
        const float* pd = dil + ((size_t)(n*NCC + k))*PP + p0;
        e[k][0]  = *(const float4*)pe;     e[k][1]  = *(const float4*)(pe + 4);
        dv[k][0] = *(const float4*)pd;     dv[k][1] = *(const float4*)(pd + 4);
    }

    __shared__ float sacc[CC][9];
    for (int t = threadIdx.x; t < CC*9; t += 256) ((float*)sacc)[t] = 0.f;
    __syncthreads();

    for (int c = 0; c < CC; ++c) {
        const float* pf = feat + ((size_t)(n*CC + c))*PP + p0;
        float4 fa = *(const float4*)pf, fb = *(const float4*)(pf + 4);
        float vals[9];
#pragma unroll
        for (int k = 0; k < NCC; ++k) {
            vals[k]     = dot8(fa, fb, e[k][0],  e[k][1]);
            vals[4 + k] = dot8(fa, fb, dv[k][0], dv[k][1]);
        }
        vals[8] = fa.x + fa.y + fa.z + fa.w + fb.x + fb.y + fb.z + fb.w;
#pragma unroll
        for (int q = 0; q < 9; ++q) {
            float r = wave_reduce(vals[q]);
            if ((threadIdx.x & 63) == 0) atomicAdd(&sacc[c][q], r);
        }
    }
    __syncthreads();
    for (int t = threadIdx.x; t < CC*9; t += 256) {
        int c = t / 9, q = t % 9;
        float v = sacc[c][q];
        if (q < 4)      atomicAdd(&dot_e[(n*CC + c)*NCC + q], v);
        else if (q < 8) atomicAdd(&dot_d[(n*CC + c)*NCC + (q - 4)], v);
        else            atomicAdd(&fsum[n*CC + c], v);
    }
}

// ---- K5: cluster[n][k][c][{fore,back}] ----
__global__ __launch_bounds__(256) void k_cluster(const float* __restrict__ dot_e,
                                                 const float* __restrict__ dot_d,
                                                 const float* __restrict__ fsum,
                                                 const float* __restrict__ esum,
                                                 const float* __restrict__ dsum,
                                                 float* __restrict__ cluster) {
    int t = threadIdx.x;              // 256 = N*NC*C
    int n = t / (NCC*CC);
    int k = (t / CC) % NCC;
    int c = t % CC;
    float de = dot_e[(n*CC + c)*NCC + k];
    float dd = dot_d[(n*CC + c)*NCC + k];
    float fs = fsum[n*CC + c];
    float es = esum[n*NCC + k] + EPS;
    float ds = dsum[n*NCC + k] + EPS;
    float bs = (float)PP - dsum[n*NCC + k] + EPS;
    float ec = de / es, dc = dd / ds, bc = (fs - dd) / bs;
    cluster[((n*NCC + k)*CC + c)*2 + 0] = ec + dc;
    cluster[((n*NCC + k)*CC + c)*2 + 1] = bc;
}

// ---- shared attn core: per-thread float4 of p, computes softmax weights s4[8]
//      (s4[2k+j] = softmaxed sim for class k, branch j, for the 4 p's). ----
__device__ __forceinline__ void attn_weights(const float* __restrict__ fb,
                                             const float* __restrict__ cl,
                                             float4* s4) {
#pragma unroll
    for (int q = 0; q < 8; ++q) s4[q] = make_float4(0.f, 0.f, 0.f, 0.f);
#pragma unroll 4
    for (int c = 0; c < CC; ++c) {
        float4 f4 = *(const float4*)(fb + (size_t)c*PP);
#pragma unroll
        for (int k = 0; k < NCC; ++k) {
            float2 cv = *(const float2*)(cl + (k*CC + c)*2);
            s4[2*k].x   += f4.x*cv.x; s4[2*k].y   += f4.y*cv.x;
            s4[2*k].z   += f4.z*cv.x; s4[2*k].w   += f4.w*cv.x;
            s4[2*k+1].x += f4.x*cv.y; s4[2*k+1].y += f4.y*cv.y;
            s4[2*k+1].z += f4.z*cv.y; s4[2*k+1].w += f4.w*cv.y;
        }
    }
#pragma unroll
    for (int k = 0; k < NCC; ++k) {
        float4 a = s4[2*k], b = s4[2*k+1];
#define SMC(C) { float m = fmaxf(a.C, b.C); \
                 float e0 = __expf(a.C - m), e1 = __expf(b.C - m); \
                 float r = 1.f / (e0 + e1); \
                 s4[2*k].C = e0*r; s4[2*k+1].C = e1*r; }
        SMC(x) SMC(y) SMC(z) SMC(w)
#undef SMC
    }
}

// ---- K6a: attn + BN stats, register-only (no out write). Thread owns 4 p. ----
__global__ __launch_bounds__(256, 4) void k_attn_stats(const float* __restrict__ feat,
                                                       const float* __restrict__ cluster,
                                                       const float* __restrict__ kptr,
                                                       float* __restrict__ bnsum,
                                                       float* __restrict__ bnsq) {
    __shared__ float cl[NCC*CC*2];        // 256
    __shared__ float sacc[CC][2];
    const int blocks_per_n = PP / 1024;   // 864
    int b = blockIdx.x;
    int n = b / blocks_per_n;
    int p0 = (b % blocks_per_n) * 1024 + threadIdx.x * 4;
    int t = threadIdx.x;

    cl[t] = cluster[n*NCC*CC*2 + t];
    if (t < CC*2) ((float*)sacc)[t] = 0.f;
    __syncthreads();

    const float* fb = feat + (size_t)n*CC*PP + p0;
    float4 s4[8];
    attn_weights(fb, cl, s4);
    float kk = kptr[0];

#pragma unroll 4
    for (int c = 0; c < CC; ++c) {
        float4 f4 = *(const float4*)(fb + (size_t)c*PP);   // L2-hot re-read
        float4 a4 = make_float4(0.f, 0.f, 0.f, 0.f);
#pragma unroll
        for (int k = 0; k < NCC; ++k) {
            float2 cv = *(const float2*)(cl + (k*CC + c)*2);
            a4.x += s4[2*k].x*cv.x + s4[2*k+1].x*cv.y;
            a4.y += s4[2*k].y*cv.x + s4[2*k+1].y*cv.y;
            a4.z += s4[2*k].z*cv.x + s4[2*k+1].z*cv.y;
            a4.w += s4[2*k].w*cv.x + s4[2*k+1].w*cv.y;
        }
        float ox = 5.f*f4.x + kk*a4.x;
        float oy = 5.f*f4.y + kk*a4.y;
        float oz = 5.f*f4.z + kk*a4.z;
        float ow = 5.f*f4.w + kk*a4.w;
        float so = ox + oy + oz + ow;
        float sq = ox*ox + oy*oy + oz*oz + ow*ow;
        so = wave_reduce(so); sq = wave_reduce(sq);
        if ((t & 63) == 0) { atomicAdd(&sacc[c][0], so); atomicAdd(&sacc[c][1], sq); }
    }
    __syncthreads();
    if (t < CC) {
        atomicAdd(&bnsum[t], sacc[t][0]);
        atomicAdd(&bnsq[t],  sacc[t][1]);
    }
}

// ---- K8: BN finalize ----
__global__ __launch_bounds__(64) void k_bnfin(const float* __restrict__ bnsum,
                                              const float* __restrict__ bnsq,
                                              const float* __restrict__ wgt,
                                              const float* __restrict__ bias,
                                              float* __restrict__ scale,
                                              float* __restrict__ shift) {
    int c = threadIdx.x;
    if (c < CC) {
        float inv_n = 1.f / (float)((size_t)NN * PP);
        float mean = bnsum[c] * inv_n;
        float var  = bnsq[c] * inv_n - mean*mean;
        float inv  = 1.f / sqrtf(var + EPS);
        float sc = wgt[c] * inv;
        scale[c] = sc;
        shift[c] = bias[c] - mean*sc;
    }
}

// ---- K6b: recompute attn, write normalized out directly (single out write). ----
__global__ __launch_bounds__(256, 4) void k_attn_write(const float* __restrict__ feat,
                                                       const float* __restrict__ cluster,
                                                       const float* __restrict__ kptr,
                                                       const float* __restrict__ scale,
                                                       const float* __restrict__ shift,
                                                       float* __restrict__ out) {
    __shared__ float cl[NCC*CC*2];        // 256
    __shared__ float scl[CC], ssh[CC];
    const int blocks_per_n = PP / 1024;   // 864
    int b = blockIdx.x;
    int n = b / blocks_per_n;
    int p0 = (b % blocks_per_n) * 1024 + threadIdx.x * 4;
    int t = threadIdx.x;

    cl[t] = cluster[n*NCC*CC*2 + t];
    if (t < CC) { scl[t] = scale[t]; ssh[t] = shift[t]; }
    __syncthreads();

    const float* fb = feat + (size_t)n*CC*PP + p0;
    float4 s4[8];
    attn_weights(fb, cl, s4);
    float kk = kptr[0];
    float* ob = out + (size_t)n*CC*PP + p0;

#pragma unroll 4
    for (int c = 0; c < CC; ++c) {
        float4 f4 = *(const float4*)(fb + (size_t)c*PP);   // L2-hot re-read
        float4 a4 = make_float4(0.f, 0.f, 0.f, 0.f);
#pragma unroll
        for (int k = 0; k < NCC; ++k) {
            float2 cv = *(const float2*)(cl + (k*CC + c)*2);
            a4.x += s4[2*k].x*cv.x + s4[2*k+1].x*cv.y;
            a4.y += s4[2*k].y*cv.x + s4[2*k+1].y*cv.y;
            a4.z += s4[2*k].z*cv.x + s4[2*k+1].z*cv.y;
            a4.w += s4[2*k].w*cv.x + s4[2*k+1].w*cv.y;
        }
        float sc = scl[c], sh = ssh[c];
        float4 o;
        o.x = (5.f*f4.x + kk*a4.x)*sc + sh;
        o.y = (5.f*f4.y + kk*a4.y)*sc + sh;
        o.z = (5.f*f4.z + kk*a4.z)*sc + sh;
        o.w = (5.f*f4.w + kk*a4.w)*sc + sh;
        *(float4*)(ob + (size_t)c*PP) = o;
    }
}

extern "C" void kernel_launch(void* const* d_in, const int* in_sizes, int n_in,
                              void* d_out, int out_size, void* d_ws, size_t ws_size,
                              hipStream_t stream) {
    const float* feat = (const float*)d_in[0];
    const float* x    = (const float*)d_in[1];
    const float* kp   = (const float*)d_in[2];
    const float* bnw  = (const float*)d_in[3];
    const float* bnb  = (const float*)d_in[4];
    float* out = (float*)d_out;
    float* ws  = (float*)d_ws;

    float* mask = ws;
    float* t0   = ws + 1*(size_t)NCP;
    float* t1   = ws + 2*(size_t)NCP;
    float* t2   = ws + 3*(size_t)NCP;
    float* dil  = ws + 4*(size_t)NCP;
    float* ero  = ws + 5*(size_t)NCP;
    float* acc  = ws + 6*(size_t)NCP;
    float* dot_e   = acc;          // 256
    float* dot_d   = acc + 256;    // 256
    float* fsum    = acc + 512;    // 64
    float* esum    = acc + 576;    // 8
    float* dsum    = acc + 584;    // 8
    float* bnsum   = acc + 592;    // 32
    float* bnsq    = acc + 624;    // 32
    float* cluster = acc + 656;    // 512
    float* scale   = acc + 1168;   // 32
    float* shift   = acc + 1200;   // 32

    hipMemsetAsync(acc, 0, 1232 * sizeof(float), stream);

    k_poolH     <<<NCP/1024, 256, 0, stream>>>(x, mask, t0, t1);
    k_poolW     <<<NCP/1024, 256, 0, stream>>>(t0, mask, t2, t1);
    k_poolD     <<<NCP/1024, 256, 0, stream>>>(t2, mask, t1, dil, ero, esum, dsum);
    k_dots      <<<NN*(PP/2048), 256, 0, stream>>>(feat, ero, dil, dot_e, dot_d, fsum);
    k_cluster   <<<1, 256, 0, stream>>>(dot_e, dot_d, fsum, esum, dsum, cluster);
    k_attn_stats<<<NN*(PP/1024), 256, 0, stream>>>(feat, cluster, kp, bnsum, bnsq);
    k_bnfin     <<<1, 64, 0, stream>>>(bnsum, bnsq, bnw, bnb, scale, shift);
    k_attn_write<<<NN*(PP/1024), 256, 0, stream>>>(feat, cluster, kp, scale, shift, out);
}

// Round 2
// 746.634 us; speedup vs baseline: 1.2727x; 1.1610x over previous
//
#include <hip/hip_runtime.h>

#define NN 2
#define CC 32
#define NCC 4
#define DD 96
#define WW 96
#define HH 96
#define PP (DD*WW*HH)          // 884736
#define NCP (NN*NCC*PP)        // 7077888
#define SD (WW*HH)             // 9216
#define SW HH                  // 96
#define EPS 1e-5f
#define BIGF 1e30f

#define PD_BLOCKS (NCP/1024)   // 6912 poolD blocks
#define PD_PER_NK (PP/1024)    // 864 poolD blocks per (n,k)

__device__ __forceinline__ float wave_reduce(float v) {
#pragma unroll
    for (int off = 32; off > 0; off >>= 1) v += __shfl_down(v, off, 64);
    return v;
}

__device__ __forceinline__ float dot8(float4 a0, float4 a1, float4 b0, float4 b1) {
    return a0.x*b0.x + a0.y*b0.y + a0.z*b0.z + a0.w*b0.w
         + a1.x*b1.x + a1.y*b1.y + a1.z*b1.z + a1.w*b1.w;
}

__device__ __forceinline__ float sigf(float v) { return 1.f / (1.f + __expf(-v)); }

__device__ __forceinline__ float4 max4(float4 a, float4 b) {
    return make_float4(fmaxf(a.x,b.x), fmaxf(a.y,b.y), fmaxf(a.z,b.z), fmaxf(a.w,b.w));
}
__device__ __forceinline__ float4 min4(float4 a, float4 b) {
    return make_float4(fminf(a.x,b.x), fminf(a.y,b.y), fminf(a.z,b.z), fminf(a.w,b.w));
}

// ---- K1: fused sigmoid + 1-D pool along H. Thread owns 4 consecutive h.
//      mask=sigmoid(x); omax=maxH(mask); omin=minH(mask).
//      Neighbor indices are CLAMPED (duplicate of an in-window value is a
//      no-op for min/max) -> branch-free, loads issue together. ----
__global__ __launch_bounds__(256) void k_poolH(const float* __restrict__ x,
                                               float* __restrict__ mask,
                                               float* __restrict__ omax,
                                               float* __restrict__ omin) {
    int i = (blockIdx.x * 256 + threadIdx.x) * 4;
    int h0 = i % HH;                       // multiple of 4
    int rb = i - h0;
    float4 xv = *(const float4*)(x + i);
    float xm2 = x[rb + (h0 > 2 ? h0 - 2 : 0)];
    float xm1 = x[rb + (h0 > 1 ? h0 - 1 : 0)];
    float xp4 = x[rb + (h0 + 4 < HH ? h0 + 4 : HH - 1)];
    float xp5 = x[rb + (h0 + 5 < HH ? h0 + 5 : HH - 1)];
    float v0 = sigf(xv.x), v1 = sigf(xv.y), v2 = sigf(xv.z), v3 = sigf(xv.w);
    float aV = sigf(xm2), bV = sigf(xm1), cV = sigf(xp4), dV = sigf(xp5);
    float4 mo, mx, mn;
    mo.x = v0; mo.y = v1; mo.z = v2; mo.w = v3;
    mx.x = fmaxf(fmaxf(aV, bV), fmaxf(fmaxf(v0, v1), v2));
    mx.y = fmaxf(bV, fmaxf(fmaxf(v0, v1), fmaxf(v2, v3)));
    mx.z = fmaxf(fmaxf(fmaxf(v0, v1), fmaxf(v2, v3)), cV);
    mx.w = fmaxf(fmaxf(v1, v2), fmaxf(v3, fmaxf(cV, dV)));
    mn.x = fminf(fminf(aV, bV), fminf(fminf(v0, v1), v2));
    mn.y = fminf(bV, fminf(fminf(v0, v1), fminf(v2, v3)));
    mn.z = fminf(fminf(fminf(v0, v1), fminf(v2, v3)), cV);
    mn.w = fminf(fminf(v1, v2), fminf(v3, fminf(cV, dV)));
    *(float4*)(mask + i) = mo;
    *(float4*)(omax + i) = mx;
    *(float4*)(omin + i) = mn;
}

// ---- K2: pool along W. omax = maxW(tmax); iomin = min(iomin, minW(mask)).
//      Clamped rows + all 11 loads preloaded into distinct regs (ILP). ----
__global__ __launch_bounds__(256) void k_poolW(const float* __restrict__ tmax,
                                               const float* __restrict__ m,
                                               float* __restrict__ omax,
                                               float* __restrict__ iomin) {
    int i = (blockIdx.x * 256 + threadIdx.x) * 4;
    int w = (i / HH) % WW;
    int o0 = ((w > 2 ? w - 2 : 0) - w) * SW;
    int o1 = ((w > 1 ? w - 1 : 0) - w) * SW;
    int o3 = ((w + 1 < WW ? w + 1 : WW - 1) - w) * SW;
    int o4 = ((w + 2 < WW ? w + 2 : WW - 1) - w) * SW;
    const float* ta = tmax + i;
    const float* mm = m + i;
    float4 a0 = *(const float4*)(ta + o0);
    float4 a1 = *(const float4*)(ta + o1);
    float4 a2 = *(const float4*)(ta);
    float4 a3 = *(const float4*)(ta + o3);
    float4 a4 = *(const float4*)(ta + o4);
    float4 b0 = *(const float4*)(mm + o0);
    float4 b1 = *(const float4*)(mm + o1);
    float4 b2 = *(const float4*)(mm);
    float4 b3 = *(const float4*)(mm + o3);
    float4 b4 = *(const float4*)(mm + o4);
    float4 prev = *(const float4*)(iomin + i);
    float4 mx = max4(max4(max4(a0, a1), max4(a2, a3)), a4);
    float4 mn = min4(min4(min4(b0, b1), min4(b2, b3)), b4);
    *(float4*)(omax + i) = mx;
    *(float4*)(iomin + i) = min4(prev, mn);
}

// ---- K3: pool along D. dil = maxD(tmax); ero = min(min12, minD(mask));
//      per-block partial esum/dsum written with plain stores (no atomics). ----
__global__ __launch_bounds__(256) void k_poolD(const float* __restrict__ tmax,
                                               const float* __restrict__ m,
                                               const float* __restrict__ min12,
                                               float* __restrict__ dil,
                                               float* __restrict__ ero,
                                               float* __restrict__ epart,
                                               float* __restrict__ dpart) {
    int base = blockIdx.x * 1024;
    int i = base + threadIdx.x * 4;
    int d = (i / SD) % DD;
    int o0 = ((d > 2 ? d - 2 : 0) - d) * SD;
    int o1 = ((d > 1 ? d - 1 : 0) - d) * SD;
    int o3 = ((d + 1 < DD ? d + 1 : DD - 1) - d) * SD;
    int o4 = ((d + 2 < DD ? d + 2 : DD - 1) - d) * SD;
    const float* ta = tmax + i;
    const float* mm = m + i;
    float4 a0 = *(const float4*)(ta + o0);
    float4 a1 = *(const float4*)(ta + o1);
    float4 a2 = *(const float4*)(ta);
    float4 a3 = *(const float4*)(ta + o3);
    float4 a4 = *(const float4*)(ta + o4);
    float4 b0 = *(const float4*)(mm + o0);
    float4 b1 = *(const float4*)(mm + o1);
    float4 b2 = *(const float4*)(mm);
    float4 b3 = *(const float4*)(mm + o3);
    float4 b4 = *(const float4*)(mm + o4);
    float4 m12 = *(const float4*)(min12 + i);
    float4 mx = max4(max4(max4(a0, a1), max4(a2, a3)), a4);
    float4 mn = min4(min4(min4(b0, b1), min4(b2, b3)), b4);
    float4 ev = min4(m12, mn);
    *(float4*)(dil + i) = mx;
    *(float4*)(ero + i) = ev;
    float ae = ev.x + ev.y + ev.z + ev.w;
    float ad = mx.x + mx.y + mx.z + mx.w;
    ae = wave_reduce(ae); ad = wave_reduce(ad);
    __shared__ float se, sdv;
    if (threadIdx.x == 0) { se = 0.f; sdv = 0.f; }
    __syncthreads();
    if ((threadIdx.x & 63) == 0) { atomicAdd(&se, ae); atomicAdd(&sdv, ad); }
    __syncthreads();
    if (threadIdx.x == 0) { epart[blockIdx.x] = se; dpart[blockIdx.x] = sdv; }
}

// ---- K4: split-K dots. Per (n,c): dot_e[k], dot_d[k], fsum. ----
__global__ __launch_bounds__(256, 2) void k_dots(const float* __restrict__ feat,
                                                 const float* __restrict__ ero,
                                                 const float* __restrict__ dil,
                                                 float* __restrict__ dot_e,
                                                 float* __restrict__ dot_d,
                                                 float* __restrict__ fsum) {
    const int chunks_per_n = PP / 2048;   // 432
    int b = blockIdx.x;
    int n = b / chunks_per_n;
    int p0 = (b % chunks_per_n) * 2048 + threadIdx.x * 8;

    float4 e[NCC][2], dv[NCC][2];
#pragma unroll
    for (int k = 0; k < NCC; ++k) {
        const float* pe = ero + ((size_t)(n*NCC + k))*PP + p0;
        const float* pd = dil + ((size_t)(n*NCC + k))*PP + p0;
        e[k][0]  = *(const float4*)pe;     e[k][1]  = *(const float4*)(pe + 4);
        dv[k][0] = *(const float4*)pd;     dv[k][1] = *(const float4*)(pd + 4);
    }

    __shared__ float sacc[CC][9];
    for (int t = threadIdx.x; t < CC*9; t += 256) ((float*)sacc)[t] = 0.f;
    __syncthreads();

    for (int c = 0; c < CC; ++c) {
        const float* pf = feat + ((size_t)(n*CC + c))*PP + p0;
        float4 fa = *(const float4*)pf, fb = *(const float4*)(pf + 4);
        float vals[9];
#pragma unroll
        for (int k = 0; k < NCC; ++k) {
            vals[k]     = dot8(fa, fb, e[k][0],  e[k][1]);
            vals[4 + k] = dot8(fa, fb, dv[k][0], dv[k][1]);
        }
        vals[8] = fa.x + fa.y + fa.z + fa.w + fb.x + fb.y + fb.z + fb.w;
#pragma unroll
        for (int q = 0; q < 9; ++q) {
            float r = wave_reduce(vals[q]);
            if ((threadIdx.x & 63) == 0) atomicAdd(&sacc[c][q], r);
        }
    }
    __syncthreads();
    for (int t = threadIdx.x; t < CC*9; t += 256) {
        int c = t / 9, q = t % 9;
        float v = sacc[c][q];
        if (q < 4)      atomicAdd(&dot_e[(n*CC + c)*NCC + q], v);
        else if (q < 8) atomicAdd(&dot_d[(n*CC + c)*NCC + (q - 4)], v);
        else            atomicAdd(&fsum[n*CC + c], v);
    }
}

// ---- K5: reduce esum/dsum partials, then cluster[n][k][c][{fore,back}] ----
__global__ __launch_bounds__(256) void k_cluster(const float* __restrict__ dot_e,
                                                 const float* __restrict__ dot_d,
                                                 const float* __restrict__ fsum,
                                                 const float* __restrict__ epart,
                                                 const float* __restrict__ dpart,
                                                 float* __restrict__ cluster) {
    __shared__ float es_s[NN*NCC], ds_s[NN*NCC];
    int t = threadIdx.x;              // 256 = N*NC*C
    {
        int nk = t >> 5, ln = t & 31;     // 8 groups x 32 lanes
        float pe = 0.f, pd = 0.f;
        for (int j = ln; j < PD_PER_NK; j += 32) {
            pe += epart[nk*PD_PER_NK + j];
            pd += dpart[nk*PD_PER_NK + j];
        }
#pragma unroll
        for (int off = 16; off > 0; off >>= 1) {
            pe += __shfl_down(pe, off, 32);
            pd += __shfl_down(pd, off, 32);
        }
        if (ln == 0) { es_s[nk] = pe; ds_s[nk] = pd; }
    }
    __syncthreads();
    int n = t / (NCC*CC);
    int k = (t / CC) % NCC;
    int c = t % CC;
    float de = dot_e[(n*CC + c)*NCC + k];
    float dd = dot_d[(n*CC + c)*NCC + k];
    float fs = fsum[n*CC + c];
    float es = es_s[n*NCC + k] + EPS;
    float ds = ds_s[n*NCC + k] + EPS;
    float bs = (float)PP - ds_s[n*NCC + k] + EPS;
    float ec = de / es, dc = dd / ds, bc = (fs - dd) / bs;
    cluster[((n*NCC + k)*CC + c)*2 + 0] = ec + dc;
    cluster[((n*NCC + k)*CC + c)*2 + 1] = bc;
}

// ---- shared attn core: per-thread float4 of p, computes softmax weights s4[8]
//      (s4[2k+j] = softmaxed sim for class k, branch j, for the 4 p's). ----
__device__ __forceinline__ void attn_weights(const float* __restrict__ fb,
                                             const float* __restrict__ cl,
                                             float4* s4) {
#pragma unroll
    for (int q = 0; q < 8; ++q) s4[q] = make_float4(0.f, 0.f, 0.f, 0.f);
#pragma unroll 4
    for (int c = 0; c < CC; ++c) {
        float4 f4 = *(const float4*)(fb + (size_t)c*PP);
#pragma unroll
        for (int k = 0; k < NCC; ++k) {
            float2 cv = *(const float2*)(cl + (k*CC + c)*2);
            s4[2*k].x   += f4.x*cv.x; s4[2*k].y   += f4.y*cv.x;
            s4[2*k].z   += f4.z*cv.x; s4[2*k].w   += f4.w*cv.x;
            s4[2*k+1].x += f4.x*cv.y; s4[2*k+1].y += f4.y*cv.y;
            s4[2*k+1].z += f4.z*cv.y; s4[2*k+1].w += f4.w*cv.y;
        }
    }
#pragma unroll
    for (int k = 0; k < NCC; ++k) {
        float4 a = s4[2*k], b = s4[2*k+1];
#define SMC(C) { float m = fmaxf(a.C, b.C); \
                 float e0 = __expf(a.C - m), e1 = __expf(b.C - m); \
                 float r = 1.f / (e0 + e1); \
                 s4[2*k].C = e0*r; s4[2*k+1].C = e1*r; }
        SMC(x) SMC(y) SMC(z) SMC(w)
#undef SMC
    }
}

// ---- K6a: attn + BN stats, register-only (no out write). Thread owns 4 p.
//      bnsum/bnsq are padded: one cache line (16 floats) per channel. ----
__global__ __launch_bounds__(256, 4) void k_attn_stats(const float* __restrict__ feat,
                                                       const float* __restrict__ cluster,
                                                       const float* __restrict__ kptr,
                                                       float* __restrict__ bnsum,
                                                       float* __restrict__ bnsq) {
    __shared__ float cl[NCC*CC*2];        // 256
    __shared__ float sacc[CC][2];
    const int blocks_per_n = PP / 1024;   // 864
    int b = blockIdx.x;
    int n = b / blocks_per_n;
    int p0 = (b % blocks_per_n) * 1024 + threadIdx.x * 4;
    int t = threadIdx.x;

    cl[t] = cluster[n*NCC*CC*2 + t];
    if (t < CC*2) ((float*)sacc)[t] = 0.f;
    __syncthreads();

    const float* fb = feat + (size_t)n*CC*PP + p0;
    float4 s4[8];
    attn_weights(fb, cl, s4);
    float kk = kptr[0];

#pragma unroll 4
    for (int c = 0; c < CC; ++c) {
        float4 f4 = *(const float4*)(fb + (size_t)c*PP);   // L2-hot re-read
        float4 a4 = make_float4(0.f, 0.f, 0.f, 0.f);
#pragma unroll
        for (int k = 0; k < NCC; ++k) {
            float2 cv = *(const float2*)(cl + (k*CC + c)*2);
            a4.x += s4[2*k].x*cv.x + s4[2*k+1].x*cv.y;
            a4.y += s4[2*k].y*cv.x + s4[2*k+1].y*cv.y;
            a4.z += s4[2*k].z*cv.x + s4[2*k+1].z*cv.y;
            a4.w += s4[2*k].w*cv.x + s4[2*k+1].w*cv.y;
        }
        float ox = 5.f*f4.x + kk*a4.x;
        float oy = 5.f*f4.y + kk*a4.y;
        float oz = 5.f*f4.z + kk*a4.z;
        float ow = 5.f*f4.w + kk*a4.w;
        float so = ox + oy + oz + ow;
        float sq = ox*ox + oy*oy + oz*oz + ow*ow;
        so = wave_reduce(so); sq = wave_reduce(sq);
        if ((t & 63) == 0) { atomicAdd(&sacc[c][0], so); atomicAdd(&sacc[c][1], sq); }
    }
    __syncthreads();
    if (t < CC) {
        atomicAdd(&bnsum[t*16], sacc[t][0]);
        atomicAdd(&bnsq[t*16],  sacc[t][1]);
    }
}

// ---- K8: BN finalize (padded stats in) ----
__global__ __launch_bounds__(64) void k_bnfin(const float* __restrict__ bnsum,
                                              const float* __restrict__ bnsq,
                                              const float* __restrict__ wgt,
                                              const float* __restrict__ bias,
                                              float* __restrict__ scale,
                                              float* __restrict__ shift) {
    int c = threadIdx.x;
    if (c < CC) {
        float inv_n = 1.f / (float)((size_t)NN * PP);
        float mean = bnsum[c*16] * inv_n;
        float var  = bnsq[c*16] * inv_n - mean*mean;
        float inv  = 1.f / sqrtf(var + EPS);
        float sc = wgt[c] * inv;
        scale[c] = sc;
        shift[c] = bias[c] - mean*sc;
    }
}

// ---- K6b: recompute attn, write normalized out directly (single out write). ----
__global__ __launch_bounds__(256, 4) void k_attn_write(const float* __restrict__ feat,
                                                       const float* __restrict__ cluster,
                                                       const float* __restrict__ kptr,
                                                       const float* __restrict__ scale,
                                                       const float* __restrict__ shift,
                                                       float* __restrict__ out) {
    __shared__ float cl[NCC*CC*2];        // 256
    __shared__ float scl[CC], ssh[CC];
    const int blocks_per_n = PP / 1024;   // 864
    int b = blockIdx.x;
    int n = b / blocks_per_n;
    int p0 = (b % blocks_per_n) * 1024 + threadIdx.x * 4;
    int t = threadIdx.x;

    cl[t] = cluster[n*NCC*CC*2 + t];
    if (t < CC) { scl[t] = scale[t]; ssh[t] = shift[t]; }
    __syncthreads();

    const float* fb = feat + (size_t)n*CC*PP + p0;
    float4 s4[8];
    attn_weights(fb, cl, s4);
    float kk = kptr[0];
    float* ob = out + (size_t)n*CC*PP + p0;

#pragma unroll 4
    for (int c = 0; c < CC; ++c) {
        float4 f4 = *(const float4*)(fb + (size_t)c*PP);   // L2-hot re-read
        float4 a4 = make_float4(0.f, 0.f, 0.f, 0.f);
#pragma unroll
        for (int k = 0; k < NCC; ++k) {
            float2 cv = *(const float2*)(cl + (k*CC + c)*2);
            a4.x += s4[2*k].x*cv.x + s4[2*k+1].x*cv.y;
            a4.y += s4[2*k].y*cv.x + s4[2*k+1].y*cv.y;
            a4.z += s4[2*k].z*cv.x + s4[2*k+1].z*cv.y;
            a4.w += s4[2*k].w*cv.x + s4[2*k+1].w*cv.y;
        }
        float sc = scl[c], sh = ssh[c];
        float4 o;
        o.x = (5.f*f4.x + kk*a4.x)*sc + sh;
        o.y = (5.f*f4.y + kk*a4.y)*sc + sh;
        o.z = (5.f*f4.z + kk*a4.z)*sc + sh;
        o.w = (5.f*f4.w + kk*a4.w)*sc + sh;
        *(float4*)(ob + (size_t)c*PP) = o;
    }
}

extern "C" void kernel_launch(void* const* d_in, const int* in_sizes, int n_in,
                              void* d_out, int out_size, void* d_ws, size_t ws_size,
                              hipStream_t stream) {
    const float* feat = (const float*)d_in[0];
    const float* x    = (const float*)d_in[1];
    const float* kp   = (const float*)d_in[2];
    const float* bnw  = (const float*)d_in[3];
    const float* bnb  = (const float*)d_in[4];
    float* out = (float*)d_out;
    float* ws  = (float*)d_ws;

    float* mask = ws;
    float* t0   = ws + 1*(size_t)NCP;
    float* t1   = ws + 2*(size_t)NCP;
    float* t2   = ws + 3*(size_t)NCP;
    float* dil  = ws + 4*(size_t)NCP;
    float* ero  = ws + 5*(size_t)NCP;
    float* acc  = ws + 6*(size_t)NCP;
    float* dot_e   = acc;          // 256
    float* dot_d   = acc + 256;    // 256
    float* fsum    = acc + 512;    // 64
    float* bnsum   = acc + 576;    // 512 (32 ch x 16 stride, padded)
    float* bnsq    = acc + 1088;   // 512 (padded)
    float* cluster = acc + 1600;   // 512
    float* scale   = acc + 2112;   // 32
    float* shift   = acc + 2144;   // 32
    float* epart   = acc + 2176;   // 6912
    float* dpart   = acc + 2176 + PD_BLOCKS;  // 6912

    hipMemsetAsync(acc, 0, 1600 * sizeof(float), stream);

    k_poolH     <<<NCP/1024, 256, 0, stream>>>(x, mask, t0, t1);
    k_poolW     <<<NCP/1024, 256, 0, stream>>>(t0, mask, t2, t1);
    k_poolD     <<<PD_BLOCKS, 256, 0, stream>>>(t2, mask, t1, dil, ero, epart, dpart);
    k_dots      <<<NN*(PP/2048), 256, 0, stream>>>(feat, ero, dil, dot_e, dot_d, fsum);
    k_cluster   <<<1, 256, 0, stream>>>(dot_e, dot_d, fsum, epart, dpart, cluster);
    k_attn_stats<<<NN*(PP/1024), 256, 0, stream>>>(feat, cluster, kp, bnsum, bnsq);
    k_bnfin     <<<1, 64, 0, stream>>>(bnsum, bnsq, bnw, bnb, scale, shift);
    k_attn_write<<<NN*(PP/1024), 256, 0, stream>>>(feat, cluster, kp, scale, shift, out);
}

// Round 3
// 746.443 us; speedup vs baseline: 1.2730x; 1.0003x over previous
//
#include <hip/hip_runtime.h>

#define NN 2
#define CC 32
#define NCC 4
#define DD 96
#define WW 96
#define HH 96
#define PP (DD*WW*HH)          // 884736
#define NCP (NN*NCC*PP)        // 7077888
#define SD (WW*HH)             // 9216
#define SW HH                  // 96
#define EPS 1e-5f
#define BIGF 1e30f

#define PD_BLOCKS (NCP/1024)   // 6912 poolD blocks
#define PD_PER_NK (PP/1024)    // 864 poolD blocks per (n,k)

#define DOT_SPLIT 288              // blocks per n
#define DOT_SLAB (PP/DOT_SPLIT)    // 3072 p per block
#define DOT_ITERS (DOT_SLAB/256)   // 12 iters (64 lanes x 4 floats)

__device__ __forceinline__ float wave_reduce(float v) {
#pragma unroll
    for (int off = 32; off > 0; off >>= 1) v += __shfl_down(v, off, 64);
    return v;
}

__device__ __forceinline__ float dot4(float4 a, float4 b) {
    return a.x*b.x + a.y*b.y + a.z*b.z + a.w*b.w;
}

__device__ __forceinline__ float sigf(float v) { return 1.f / (1.f + __expf(-v)); }

__device__ __forceinline__ float4 max4(float4 a, float4 b) {
    return make_float4(fmaxf(a.x,b.x), fmaxf(a.y,b.y), fmaxf(a.z,b.z), fmaxf(a.w,b.w));
}
__device__ __forceinline__ float4 min4(float4 a, float4 b) {
    return make_float4(fminf(a.x,b.x), fminf(a.y,b.y), fminf(a.z,b.z), fminf(a.w,b.w));
}

// ---- K1: fused sigmoid + 1-D pool along H. Thread owns 4 consecutive h. ----
__global__ __launch_bounds__(256) void k_poolH(const float* __restrict__ x,
                                               float* __restrict__ mask,
                                               float* __restrict__ omax,
                                               float* __restrict__ omin) {
    int i = (blockIdx.x * 256 + threadIdx.x) * 4;
    int h0 = i % HH;                       // multiple of 4
    int rb = i - h0;
    float4 xv = *(const float4*)(x + i);
    float xm2 = x[rb + (h0 > 2 ? h0 - 2 : 0)];
    float xm1 = x[rb + (h0 > 1 ? h0 - 1 : 0)];
    float xp4 = x[rb + (h0 + 4 < HH ? h0 + 4 : HH - 1)];
    float xp5 = x[rb + (h0 + 5 < HH ? h0 + 5 : HH - 1)];
    float v0 = sigf(xv.x), v1 = sigf(xv.y), v2 = sigf(xv.z), v3 = sigf(xv.w);
    float aV = sigf(xm2), bV = sigf(xm1), cV = sigf(xp4), dV = sigf(xp5);
    float4 mo, mx, mn;
    mo.x = v0; mo.y = v1; mo.z = v2; mo.w = v3;
    mx.x = fmaxf(fmaxf(aV, bV), fmaxf(fmaxf(v0, v1), v2));
    mx.y = fmaxf(bV, fmaxf(fmaxf(v0, v1), fmaxf(v2, v3)));
    mx.z = fmaxf(fmaxf(fmaxf(v0, v1), fmaxf(v2, v3)), cV);
    mx.w = fmaxf(fmaxf(v1, v2), fmaxf(v3, fmaxf(cV, dV)));
    mn.x = fminf(fminf(aV, bV), fminf(fminf(v0, v1), v2));
    mn.y = fminf(bV, fminf(fminf(v0, v1), fminf(v2, v3)));
    mn.z = fminf(fminf(fminf(v0, v1), fminf(v2, v3)), cV);
    mn.w = fminf(fminf(v1, v2), fminf(v3, fminf(cV, dV)));
    *(float4*)(mask + i) = mo;
    *(float4*)(omax + i) = mx;
    *(float4*)(omin + i) = mn;
}

// ---- K2: pool along W, clamped + preloaded (ILP). ----
__global__ __launch_bounds__(256) void k_poolW(const float* __restrict__ tmax,
                                               const float* __restrict__ m,
                                               float* __restrict__ omax,
                                               float* __restrict__ iomin) {
    int i = (blockIdx.x * 256 + threadIdx.x) * 4;
    int w = (i / HH) % WW;
    int o0 = ((w > 2 ? w - 2 : 0) - w) * SW;
    int o1 = ((w > 1 ? w - 1 : 0) - w) * SW;
    int o3 = ((w + 1 < WW ? w + 1 : WW - 1) - w) * SW;
    int o4 = ((w + 2 < WW ? w + 2 : WW - 1) - w) * SW;
    const float* ta = tmax + i;
    const float* mm = m + i;
    float4 a0 = *(const float4*)(ta + o0);
    float4 a1 = *(const float4*)(ta + o1);
    float4 a2 = *(const float4*)(ta);
    float4 a3 = *(const float4*)(ta + o3);
    float4 a4 = *(const float4*)(ta + o4);
    float4 b0 = *(const float4*)(mm + o0);
    float4 b1 = *(const float4*)(mm + o1);
    float4 b2 = *(const float4*)(mm);
    float4 b3 = *(const float4*)(mm + o3);
    float4 b4 = *(const float4*)(mm + o4);
    float4 prev = *(const float4*)(iomin + i);
    float4 mx = max4(max4(max4(a0, a1), max4(a2, a3)), a4);
    float4 mn = min4(min4(min4(b0, b1), min4(b2, b3)), b4);
    *(float4*)(omax + i) = mx;
    *(float4*)(iomin + i) = min4(prev, mn);
}

// ---- K3: pool along D; per-block partial esum/dsum (plain stores). ----
__global__ __launch_bounds__(256) void k_poolD(const float* __restrict__ tmax,
                                               const float* __restrict__ m,
                                               const float* __restrict__ min12,
                                               float* __restrict__ dil,
                                               float* __restrict__ ero,
                                               float* __restrict__ epart,
                                               float* __restrict__ dpart) {
    int base = blockIdx.x * 1024;
    int i = base + threadIdx.x * 4;
    int d = (i / SD) % DD;
    int o0 = ((d > 2 ? d - 2 : 0) - d) * SD;
    int o1 = ((d > 1 ? d - 1 : 0) - d) * SD;
    int o3 = ((d + 1 < DD ? d + 1 : DD - 1) - d) * SD;
    int o4 = ((d + 2 < DD ? d + 2 : DD - 1) - d) * SD;
    const float* ta = tmax + i;
    const float* mm = m + i;
    float4 a0 = *(const float4*)(ta + o0);
    float4 a1 = *(const float4*)(ta + o1);
    float4 a2 = *(const float4*)(ta);
    float4 a3 = *(const float4*)(ta + o3);
    float4 a4 = *(const float4*)(ta + o4);
    float4 b0 = *(const float4*)(mm + o0);
    float4 b1 = *(const float4*)(mm + o1);
    float4 b2 = *(const float4*)(mm);
    float4 b3 = *(const float4*)(mm + o3);
    float4 b4 = *(const float4*)(mm + o4);
    float4 m12 = *(const float4*)(min12 + i);
    float4 mx = max4(max4(max4(a0, a1), max4(a2, a3)), a4);
    float4 mn = min4(min4(min4(b0, b1), min4(b2, b3)), b4);
    float4 ev = min4(m12, mn);
    *(float4*)(dil + i) = mx;
    *(float4*)(ero + i) = ev;
    float ae = ev.x + ev.y + ev.z + ev.w;
    float ad = mx.x + mx.y + mx.z + mx.w;
    ae = wave_reduce(ae); ad = wave_reduce(ad);
    __shared__ float se, sdv;
    if (threadIdx.x == 0) { se = 0.f; sdv = 0.f; }
    __syncthreads();
    if ((threadIdx.x & 63) == 0) { atomicAdd(&se, ae); atomicAdd(&sdv, ad); }
    __syncthreads();
    if (threadIdx.x == 0) { epart[blockIdx.x] = se; dpart[blockIdx.x] = sdv; }
}

// ---- K4: dots, wave-private channels. Wave w owns c in [8w, 8w+8); each
//      thread keeps acc[8][9] in regs over a 3072-p slab; ONE reduction per
//      block (amortized), LDS stage (no collisions), then global atomics. ----
__global__ __launch_bounds__(256) void k_dots(const float* __restrict__ feat,
                                              const float* __restrict__ ero,
                                              const float* __restrict__ dil,
                                              float* __restrict__ dot_e,
                                              float* __restrict__ dot_d,
                                              float* __restrict__ fsum) {
    int b = blockIdx.x;
    int n = b / DOT_SPLIT;
    int slab0 = (b % DOT_SPLIT) * DOT_SLAB;
    int wv = threadIdx.x >> 6, ln = threadIdx.x & 63;
    int c0 = wv * 8;

    const float* eb = ero + (size_t)n*NCC*PP;
    const float* db = dil + (size_t)n*NCC*PP;
    const float* fb = feat + ((size_t)n*CC + c0)*PP;

    float acc[8][9];
#pragma unroll
    for (int j = 0; j < 8; ++j)
#pragma unroll
        for (int q = 0; q < 9; ++q) acc[j][q] = 0.f;

    for (int it = 0; it < DOT_ITERS; ++it) {
        int p = slab0 + it*256 + ln*4;
        float4 e0 = *(const float4*)(eb + 0*(size_t)PP + p);
        float4 e1 = *(const float4*)(eb + 1*(size_t)PP + p);
        float4 e2 = *(const float4*)(eb + 2*(size_t)PP + p);
        float4 e3 = *(const float4*)(eb + 3*(size_t)PP + p);
        float4 d0 = *(const float4*)(db + 0*(size_t)PP + p);
        float4 d1 = *(const float4*)(db + 1*(size_t)PP + p);
        float4 d2 = *(const float4*)(db + 2*(size_t)PP + p);
        float4 d3 = *(const float4*)(db + 3*(size_t)PP + p);
        float4 f[8];
#pragma unroll
        for (int j = 0; j < 8; ++j)
            f[j] = *(const float4*)(fb + (size_t)j*PP + p);
#pragma unroll
        for (int j = 0; j < 8; ++j) {
            acc[j][0] += dot4(f[j], e0);
            acc[j][1] += dot4(f[j], e1);
            acc[j][2] += dot4(f[j], e2);
            acc[j][3] += dot4(f[j], e3);
            acc[j][4] += dot4(f[j], d0);
            acc[j][5] += dot4(f[j], d1);
            acc[j][6] += dot4(f[j], d2);
            acc[j][7] += dot4(f[j], d3);
            acc[j][8] += f[j].x + f[j].y + f[j].z + f[j].w;
        }
    }

    __shared__ float sacc[CC][9];
#pragma unroll
    for (int j = 0; j < 8; ++j)
#pragma unroll
        for (int q = 0; q < 9; ++q) {
            float r = wave_reduce(acc[j][q]);
            if (ln == 0) sacc[c0 + j][q] = r;     // wave-disjoint channels
        }
    __syncthreads();
    for (int t = threadIdx.x; t < CC*9; t += 256) {
        int c = t / 9, q = t % 9;
        float v = sacc[c][q];
        if (q < 4)      atomicAdd(&dot_e[(n*CC + c)*NCC + q], v);
        else if (q < 8) atomicAdd(&dot_d[(n*CC + c)*NCC + (q - 4)], v);
        else            atomicAdd(&fsum[n*CC + c], v);
    }
}

// ---- K5: reduce esum/dsum partials, then cluster[n][k][c][{fore,back}] ----
__global__ __launch_bounds__(256) void k_cluster(const float* __restrict__ dot_e,
                                                 const float* __restrict__ dot_d,
                                                 const float* __restrict__ fsum,
                                                 const float* __restrict__ epart,
                                                 const float* __restrict__ dpart,
                                                 float* __restrict__ cluster) {
    __shared__ float es_s[NN*NCC], ds_s[NN*NCC];
    int t = threadIdx.x;              // 256 = N*NC*C
    {
        int nk = t >> 5, ln = t & 31;     // 8 groups x 32 lanes
        float pe = 0.f, pd = 0.f;
        for (int j = ln; j < PD_PER_NK; j += 32) {
            pe += epart[nk*PD_PER_NK + j];
            pd += dpart[nk*PD_PER_NK + j];
        }
#pragma unroll
        for (int off = 16; off > 0; off >>= 1) {
            pe += __shfl_down(pe, off, 32);
            pd += __shfl_down(pd, off, 32);
        }
        if (ln == 0) { es_s[nk] = pe; ds_s[nk] = pd; }
    }
    __syncthreads();
    int n = t / (NCC*CC);
    int k = (t / CC) % NCC;
    int c = t % CC;
    float de = dot_e[(n*CC + c)*NCC + k];
    float dd = dot_d[(n*CC + c)*NCC + k];
    float fs = fsum[n*CC + c];
    float es = es_s[n*NCC + k] + EPS;
    float ds = ds_s[n*NCC + k] + EPS;
    float bs = (float)PP - ds_s[n*NCC + k] + EPS;
    float ec = de / es, dc = dd / ds, bc = (fs - dd) / bs;
    cluster[((n*NCC + k)*CC + c)*2 + 0] = ec + dc;
    cluster[((n*NCC + k)*CC + c)*2 + 1] = bc;
}

// ---- shared attn core ----
__device__ __forceinline__ void attn_weights(const float* __restrict__ fb,
                                             const float* __restrict__ cl,
                                             float4* s4) {
#pragma unroll
    for (int q = 0; q < 8; ++q) s4[q] = make_float4(0.f, 0.f, 0.f, 0.f);
#pragma unroll 4
    for (int c = 0; c < CC; ++c) {
        float4 f4 = *(const float4*)(fb + (size_t)c*PP);
#pragma unroll
        for (int k = 0; k < NCC; ++k) {
            float2 cv = *(const float2*)(cl + (k*CC + c)*2);
            s4[2*k].x   += f4.x*cv.x; s4[2*k].y   += f4.y*cv.x;
            s4[2*k].z   += f4.z*cv.x; s4[2*k].w   += f4.w*cv.x;
            s4[2*k+1].x += f4.x*cv.y; s4[2*k+1].y += f4.y*cv.y;
            s4[2*k+1].z += f4.z*cv.y; s4[2*k+1].w += f4.w*cv.y;
        }
    }
#pragma unroll
    for (int k = 0; k < NCC; ++k) {
        float4 a = s4[2*k], b = s4[2*k+1];
#define SMC(C) { float m = fmaxf(a.C, b.C); \
                 float e0 = __expf(a.C - m), e1 = __expf(b.C - m); \
                 float r = 1.f / (e0 + e1); \
                 s4[2*k].C = e0*r; s4[2*k+1].C = e1*r; }
        SMC(x) SMC(y) SMC(z) SMC(w)
#undef SMC
    }
}

// ---- K6a: attn + BN stats, register-only. Padded bn accumulators. ----
__global__ __launch_bounds__(256, 4) void k_attn_stats(const float* __restrict__ feat,
                                                       const float* __restrict__ cluster,
                                                       const float* __restrict__ kptr,
                                                       float* __restrict__ bnsum,
                                                       float* __restrict__ bnsq) {
    __shared__ float cl[NCC*CC*2];        // 256
    __shared__ float sacc[CC][2];
    const int blocks_per_n = PP / 1024;   // 864
    int b = blockIdx.x;
    int n = b / blocks_per_n;
    int p0 = (b % blocks_per_n) * 1024 + threadIdx.x * 4;
    int t = threadIdx.x;

    cl[t] = cluster[n*NCC*CC*2 + t];
    if (t < CC*2) ((float*)sacc)[t] = 0.f;
    __syncthreads();

    const float* fb = feat + (size_t)n*CC*PP + p0;
    float4 s4[8];
    attn_weights(fb, cl, s4);
    float kk = kptr[0];

#pragma unroll 4
    for (int c = 0; c < CC; ++c) {
        float4 f4 = *(const float4*)(fb + (size_t)c*PP);   // L2-hot re-read
        float4 a4 = make_float4(0.f, 0.f, 0.f, 0.f);
#pragma unroll
        for (int k = 0; k < NCC; ++k) {
            float2 cv = *(const float2*)(cl + (k*CC + c)*2);
            a4.x += s4[2*k].x*cv.x + s4[2*k+1].x*cv.y;
            a4.y += s4[2*k].y*cv.x + s4[2*k+1].y*cv.y;
            a4.z += s4[2*k].z*cv.x + s4[2*k+1].z*cv.y;
            a4.w += s4[2*k].w*cv.x + s4[2*k+1].w*cv.y;
        }
        float ox = 5.f*f4.x + kk*a4.x;
        float oy = 5.f*f4.y + kk*a4.y;
        float oz = 5.f*f4.z + kk*a4.z;
        float ow = 5.f*f4.w + kk*a4.w;
        float so = ox + oy + oz + ow;
        float sq = ox*ox + oy*oy + oz*oz + ow*ow;
        so = wave_reduce(so); sq = wave_reduce(sq);
        if ((t & 63) == 0) { atomicAdd(&sacc[c][0], so); atomicAdd(&sacc[c][1], sq); }
    }
    __syncthreads();
    if (t < CC) {
        atomicAdd(&bnsum[t*16], sacc[t][0]);
        atomicAdd(&bnsq[t*16],  sacc[t][1]);
    }
}

// ---- K8: BN finalize (padded stats in) ----
__global__ __launch_bounds__(64) void k_bnfin(const float* __restrict__ bnsum,
                                              const float* __restrict__ bnsq,
                                              const float* __restrict__ wgt,
                                              const float* __restrict__ bias,
                                              float* __restrict__ scale,
                                              float* __restrict__ shift) {
    int c = threadIdx.x;
    if (c < CC) {
        float inv_n = 1.f / (float)((size_t)NN * PP);
        float mean = bnsum[c*16] * inv_n;
        float var  = bnsq[c*16] * inv_n - mean*mean;
        float inv  = 1.f / sqrtf(var + EPS);
        float sc = wgt[c] * inv;
        scale[c] = sc;
        shift[c] = bias[c] - mean*sc;
    }
}

// ---- K6b: recompute attn, write normalized out directly. ----
__global__ __launch_bounds__(256, 4) void k_attn_write(const float* __restrict__ feat,
                                                       const float* __restrict__ cluster,
                                                       const float* __restrict__ kptr,
                                                       const float* __restrict__ scale,
                                                       const float* __restrict__ shift,
                                                       float* __restrict__ out) {
    __shared__ float cl[NCC*CC*2];        // 256
    __shared__ float scl[CC], ssh[CC];
    const int blocks_per_n = PP / 1024;   // 864
    int b = blockIdx.x;
    int n = b / blocks_per_n;
    int p0 = (b % blocks_per_n) * 1024 + threadIdx.x * 4;
    int t = threadIdx.x;

    cl[t] = cluster[n*NCC*CC*2 + t];
    if (t < CC) { scl[t] = scale[t]; ssh[t] = shift[t]; }
    __syncthreads();

    const float* fb = feat + (size_t)n*CC*PP + p0;
    float4 s4[8];
    attn_weights(fb, cl, s4);
    float kk = kptr[0];
    float* ob = out + (size_t)n*CC*PP + p0;

#pragma unroll 4
    for (int c = 0; c < CC; ++c) {
        float4 f4 = *(const float4*)(fb + (size_t)c*PP);   // L2-hot re-read
        float4 a4 = make_float4(0.f, 0.f, 0.f, 0.f);
#pragma unroll
        for (int k = 0; k < NCC; ++k) {
            float2 cv = *(const float2*)(cl + (k*CC + c)*2);
            a4.x += s4[2*k].x*cv.x + s4[2*k+1].x*cv.y;
            a4.y += s4[2*k].y*cv.x + s4[2*k+1].y*cv.y;
            a4.z += s4[2*k].z*cv.x + s4[2*k+1].z*cv.y;
            a4.w += s4[2*k].w*cv.x + s4[2*k+1].w*cv.y;
        }
        float sc = scl[c], sh = ssh[c];
        float4 o;
        o.x = (5.f*f4.x + kk*a4.x)*sc + sh;
        o.y = (5.f*f4.y + kk*a4.y)*sc + sh;
        o.z = (5.f*f4.z + kk*a4.z)*sc + sh;
        o.w = (5.f*f4.w + kk*a4.w)*sc + sh;
        *(float4*)(ob + (size_t)c*PP) = o;
    }
}

extern "C" void kernel_launch(void* const* d_in, const int* in_sizes, int n_in,
                              void* d_out, int out_size, void* d_ws, size_t ws_size,
                              hipStream_t stream) {
    const float* feat = (const float*)d_in[0];
    const float* x    = (const float*)d_in[1];
    const float* kp   = (const float*)d_in[2];
    const float* bnw  = (const float*)d_in[3];
    const float* bnb  = (const float*)d_in[4];
    float* out = (float*)d_out;
    float* ws  = (float*)d_ws;

    float* mask = ws;
    float* t0   = ws + 1*(size_t)NCP;
    float* t1   = ws + 2*(size_t)NCP;
    float* t2   = ws + 3*(size_t)NCP;
    float* dil  = ws + 4*(size_t)NCP;
    float* ero  = ws + 5*(size_t)NCP;
    float* acc  = ws + 6*(size_t)NCP;
    float* dot_e   = acc;          // 256
    float* dot_d   = acc + 256;    // 256
    float* fsum    = acc + 512;    // 64
    float* bnsum   = acc + 576;    // 512 (32 ch x 16 stride, padded)
    float* bnsq    = acc + 1088;   // 512 (padded)
    float* cluster = acc + 1600;   // 512
    float* scale   = acc + 2112;   // 32
    float* shift   = acc + 2144;   // 32
    float* epart   = acc + 2176;   // 6912
    float* dpart   = acc + 2176 + PD_BLOCKS;  // 6912

    hipMemsetAsync(acc, 0, 1600 * sizeof(float), stream);

    k_poolH     <<<NCP/1024, 256, 0, stream>>>(x, mask, t0, t1);
    k_poolW     <<<NCP/1024, 256, 0, stream>>>(t0, mask, t2, t1);
    k_poolD     <<<PD_BLOCKS, 256, 0, stream>>>(t2, mask, t1, dil, ero, epart, dpart);
    k_dots      <<<NN*DOT_SPLIT, 256, 0, stream>>>(feat, ero, dil, dot_e, dot_d, fsum);
    k_cluster   <<<1, 256, 0, stream>>>(dot_e, dot_d, fsum, epart, dpart, cluster);
    k_attn_stats<<<NN*(PP/1024), 256, 0, stream>>>(feat, cluster, kp, bnsum, bnsq);
    k_bnfin     <<<1, 64, 0, stream>>>(bnsum, bnsq, bnw, bnb, scale, shift);
    k_attn_write<<<NN*(PP/1024), 256, 0, stream>>>(feat, cluster, kp, scale, shift, out);
}

// Round 4
// 725.360 us; speedup vs baseline: 1.3100x; 1.0291x over previous
//
#include <hip/hip_runtime.h>

#define NN 2
#define CC 32
#define NCC 4
#define DD 96
#define WW 96
#define HH 96
#define PP (DD*WW*HH)          // 884736
#define NCP (NN*NCC*PP)        // 7077888
#define SD (WW*HH)             // 9216
#define SW HH                  // 96
#define EPS 1e-5f
#define BIGF 1e30f

#define PD_BLOCKS (NCP/1024)   // 6912 poolD blocks
#define PD_PER_NK (PP/1024)    // 864 poolD blocks per (n,k)

#define DOT_PSPLIT 216             // p-slabs per n
#define DOT_SLAB (PP/DOT_PSPLIT)   // 4096 p per slab
#define DOT_ITERS (DOT_SLAB/256)   // 16 iters (64 lanes x 4 floats per wave-iter)

__device__ __forceinline__ float wave_reduce(float v) {
#pragma unroll
    for (int off = 32; off > 0; off >>= 1) v += __shfl_down(v, off, 64);
    return v;
}

__device__ __forceinline__ float dot4(float4 a, float4 b) {
    return a.x*b.x + a.y*b.y + a.z*b.z + a.w*b.w;
}

__device__ __forceinline__ float sigf(float v) { return 1.f / (1.f + __expf(-v)); }

__device__ __forceinline__ float4 max4(float4 a, float4 b) {
    return make_float4(fmaxf(a.x,b.x), fmaxf(a.y,b.y), fmaxf(a.z,b.z), fmaxf(a.w,b.w));
}
__device__ __forceinline__ float4 min4(float4 a, float4 b) {
    return make_float4(fminf(a.x,b.x), fminf(a.y,b.y), fminf(a.z,b.z), fminf(a.w,b.w));
}

// ---- K1: fused sigmoid + 1-D pool along H. Thread owns 4 consecutive h. ----
__global__ __launch_bounds__(256) void k_poolH(const float* __restrict__ x,
                                               float* __restrict__ mask,
                                               float* __restrict__ omax,
                                               float* __restrict__ omin) {
    int i = (blockIdx.x * 256 + threadIdx.x) * 4;
    int h0 = i % HH;                       // multiple of 4
    int rb = i - h0;
    float4 xv = *(const float4*)(x + i);
    float xm2 = x[rb + (h0 > 2 ? h0 - 2 : 0)];
    float xm1 = x[rb + (h0 > 1 ? h0 - 1 : 0)];
    float xp4 = x[rb + (h0 + 4 < HH ? h0 + 4 : HH - 1)];
    float xp5 = x[rb + (h0 + 5 < HH ? h0 + 5 : HH - 1)];
    float v0 = sigf(xv.x), v1 = sigf(xv.y), v2 = sigf(xv.z), v3 = sigf(xv.w);
    float aV = sigf(xm2), bV = sigf(xm1), cV = sigf(xp4), dV = sigf(xp5);
    float4 mo, mx, mn;
    mo.x = v0; mo.y = v1; mo.z = v2; mo.w = v3;
    mx.x = fmaxf(fmaxf(aV, bV), fmaxf(fmaxf(v0, v1), v2));
    mx.y = fmaxf(bV, fmaxf(fmaxf(v0, v1), fmaxf(v2, v3)));
    mx.z = fmaxf(fmaxf(fmaxf(v0, v1), fmaxf(v2, v3)), cV);
    mx.w = fmaxf(fmaxf(v1, v2), fmaxf(v3, fmaxf(cV, dV)));
    mn.x = fminf(fminf(aV, bV), fminf(fminf(v0, v1), v2));
    mn.y = fminf(bV, fminf(fminf(v0, v1), fminf(v2, v3)));
    mn.z = fminf(fminf(fminf(v0, v1), fminf(v2, v3)), cV);
    mn.w = fminf(fminf(v1, v2), fminf(v3, fminf(cV, dV)));
    *(float4*)(mask + i) = mo;
    *(float4*)(omax + i) = mx;
    *(float4*)(omin + i) = mn;
}

// ---- K2: pool along W, clamped + preloaded (ILP). ----
__global__ __launch_bounds__(256) void k_poolW(const float* __restrict__ tmax,
                                               const float* __restrict__ m,
                                               float* __restrict__ omax,
                                               float* __restrict__ iomin) {
    int i = (blockIdx.x * 256 + threadIdx.x) * 4;
    int w = (i / HH) % WW;
    int o0 = ((w > 2 ? w - 2 : 0) - w) * SW;
    int o1 = ((w > 1 ? w - 1 : 0) - w) * SW;
    int o3 = ((w + 1 < WW ? w + 1 : WW - 1) - w) * SW;
    int o4 = ((w + 2 < WW ? w + 2 : WW - 1) - w) * SW;
    const float* ta = tmax + i;
    const float* mm = m + i;
    float4 a0 = *(const float4*)(ta + o0);
    float4 a1 = *(const float4*)(ta + o1);
    float4 a2 = *(const float4*)(ta);
    float4 a3 = *(const float4*)(ta + o3);
    float4 a4 = *(const float4*)(ta + o4);
    float4 b0 = *(const float4*)(mm + o0);
    float4 b1 = *(const float4*)(mm + o1);
    float4 b2 = *(const float4*)(mm);
    float4 b3 = *(const float4*)(mm + o3);
    float4 b4 = *(const float4*)(mm + o4);
    float4 prev = *(const float4*)(iomin + i);
    float4 mx = max4(max4(max4(a0, a1), max4(a2, a3)), a4);
    float4 mn = min4(min4(min4(b0, b1), min4(b2, b3)), b4);
    *(float4*)(omax + i) = mx;
    *(float4*)(iomin + i) = min4(prev, mn);
}

// ---- K3: pool along D; per-block partial esum/dsum (plain stores). ----
__global__ __launch_bounds__(256) void k_poolD(const float* __restrict__ tmax,
                                               const float* __restrict__ m,
                                               const float* __restrict__ min12,
                                               float* __restrict__ dil,
                                               float* __restrict__ ero,
                                               float* __restrict__ epart,
                                               float* __restrict__ dpart) {
    int base = blockIdx.x * 1024;
    int i = base + threadIdx.x * 4;
    int d = (i / SD) % DD;
    int o0 = ((d > 2 ? d - 2 : 0) - d) * SD;
    int o1 = ((d > 1 ? d - 1 : 0) - d) * SD;
    int o3 = ((d + 1 < DD ? d + 1 : DD - 1) - d) * SD;
    int o4 = ((d + 2 < DD ? d + 2 : DD - 1) - d) * SD;
    const float* ta = tmax + i;
    const float* mm = m + i;
    float4 a0 = *(const float4*)(ta + o0);
    float4 a1 = *(const float4*)(ta + o1);
    float4 a2 = *(const float4*)(ta);
    float4 a3 = *(const float4*)(ta + o3);
    float4 a4 = *(const float4*)(ta + o4);
    float4 b0 = *(const float4*)(mm + o0);
    float4 b1 = *(const float4*)(mm + o1);
    float4 b2 = *(const float4*)(mm);
    float4 b3 = *(const float4*)(mm + o3);
    float4 b4 = *(const float4*)(mm + o4);
    float4 m12 = *(const float4*)(min12 + i);
    float4 mx = max4(max4(max4(a0, a1), max4(a2, a3)), a4);
    float4 mn = min4(min4(min4(b0, b1), min4(b2, b3)), b4);
    float4 ev = min4(m12, mn);
    *(float4*)(dil + i) = mx;
    *(float4*)(ero + i) = ev;
    float ae = ev.x + ev.y + ev.z + ev.w;
    float ad = mx.x + mx.y + mx.z + mx.w;
    ae = wave_reduce(ae); ad = wave_reduce(ad);
    __shared__ float se, sdv;
    if (threadIdx.x == 0) { se = 0.f; sdv = 0.f; }
    __syncthreads();
    if ((threadIdx.x & 63) == 0) { atomicAdd(&se, ae); atomicAdd(&sdv, ad); }
    __syncthreads();
    if (threadIdx.x == 0) { epart[blockIdx.x] = se; dpart[blockIdx.x] = sdv; }
}

// ---- K4: dots, 2 channels per wave (low VGPR -> high occupancy).
//      Block = 4 waves = 8 channels (chgroup cg), one 4096-p slab.
//      Grid = NN * 4 chgroups * 216 slabs = 1728 blocks (27 waves/CU).
//      Per iter: 8 shared e/d loads + 2 feat loads, all independent. ----
__global__ __launch_bounds__(256, 6) void k_dots(const float* __restrict__ feat,
                                                 const float* __restrict__ ero,
                                                 const float* __restrict__ dil,
                                                 float* __restrict__ dot_e,
                                                 float* __restrict__ dot_d,
                                                 float* __restrict__ fsum) {
    int b = blockIdx.x;
    int n = b / (4*DOT_PSPLIT);
    int rem = b % (4*DOT_PSPLIT);
    int cg = rem / DOT_PSPLIT;            // 0..3, channels [cg*8, cg*8+8)
    int slab = rem % DOT_PSPLIT;
    int wv = threadIdx.x >> 6, ln = threadIdx.x & 63;
    int c0 = cg*8 + wv*2;                 // this wave's 2 channels

    const float* eb = ero + (size_t)n*NCC*PP;
    const float* db = dil + (size_t)n*NCC*PP;
    const float* f0 = feat + ((size_t)n*CC + c0)*PP;
    const float* f1 = f0 + PP;
    int p0 = slab*DOT_SLAB + ln*4;

    float acc[2][9];
#pragma unroll
    for (int j = 0; j < 2; ++j)
#pragma unroll
        for (int q = 0; q < 9; ++q) acc[j][q] = 0.f;

    for (int it = 0; it < DOT_ITERS; ++it) {
        int p = p0 + it*256;
        float4 e0 = *(const float4*)(eb + 0*(size_t)PP + p);
        float4 e1 = *(const float4*)(eb + 1*(size_t)PP + p);
        float4 e2 = *(const float4*)(eb + 2*(size_t)PP + p);
        float4 e3 = *(const float4*)(eb + 3*(size_t)PP + p);
        float4 d0 = *(const float4*)(db + 0*(size_t)PP + p);
        float4 d1 = *(const float4*)(db + 1*(size_t)PP + p);
        float4 d2 = *(const float4*)(db + 2*(size_t)PP + p);
        float4 d3 = *(const float4*)(db + 3*(size_t)PP + p);
        float4 fa = *(const float4*)(f0 + p);
        float4 fb = *(const float4*)(f1 + p);
        acc[0][0] += dot4(fa, e0);  acc[1][0] += dot4(fb, e0);
        acc[0][1] += dot4(fa, e1);  acc[1][1] += dot4(fb, e1);
        acc[0][2] += dot4(fa, e2);  acc[1][2] += dot4(fb, e2);
        acc[0][3] += dot4(fa, e3);  acc[1][3] += dot4(fb, e3);
        acc[0][4] += dot4(fa, d0);  acc[1][4] += dot4(fb, d0);
        acc[0][5] += dot4(fa, d1);  acc[1][5] += dot4(fb, d1);
        acc[0][6] += dot4(fa, d2);  acc[1][6] += dot4(fb, d2);
        acc[0][7] += dot4(fa, d3);  acc[1][7] += dot4(fb, d3);
        acc[0][8] += fa.x + fa.y + fa.z + fa.w;
        acc[1][8] += fb.x + fb.y + fb.z + fb.w;
    }

    __shared__ float sacc[8][9];          // block-local channel x 9
#pragma unroll
    for (int j = 0; j < 2; ++j)
#pragma unroll
        for (int q = 0; q < 9; ++q) {
            float r = wave_reduce(acc[j][q]);
            if (ln == 0) sacc[wv*2 + j][q] = r;   // wave-disjoint rows
        }
    __syncthreads();
    if (threadIdx.x < 72) {
        int j = threadIdx.x / 9, q = threadIdx.x % 9;
        int c = cg*8 + j;
        float v = sacc[j][q];
        if (q < 4)      atomicAdd(&dot_e[(n*CC + c)*NCC + q], v);
        else if (q < 8) atomicAdd(&dot_d[(n*CC + c)*NCC + (q - 4)], v);
        else            atomicAdd(&fsum[n*CC + c], v);
    }
}

// ---- K5: reduce esum/dsum partials, then cluster[n][k][c][{fore,back}] ----
__global__ __launch_bounds__(256) void k_cluster(const float* __restrict__ dot_e,
                                                 const float* __restrict__ dot_d,
                                                 const float* __restrict__ fsum,
                                                 const float* __restrict__ epart,
                                                 const float* __restrict__ dpart,
                                                 float* __restrict__ cluster) {
    __shared__ float es_s[NN*NCC], ds_s[NN*NCC];
    int t = threadIdx.x;              // 256 = N*NC*C
    {
        int nk = t >> 5, ln = t & 31;     // 8 groups x 32 lanes
        float pe = 0.f, pd = 0.f;
        for (int j = ln; j < PD_PER_NK; j += 32) {
            pe += epart[nk*PD_PER_NK + j];
            pd += dpart[nk*PD_PER_NK + j];
        }
#pragma unroll
        for (int off = 16; off > 0; off >>= 1) {
            pe += __shfl_down(pe, off, 32);
            pd += __shfl_down(pd, off, 32);
        }
        if (ln == 0) { es_s[nk] = pe; ds_s[nk] = pd; }
    }
    __syncthreads();
    int n = t / (NCC*CC);
    int k = (t / CC) % NCC;
    int c = t % CC;
    float de = dot_e[(n*CC + c)*NCC + k];
    float dd = dot_d[(n*CC + c)*NCC + k];
    float fs = fsum[n*CC + c];
    float es = es_s[n*NCC + k] + EPS;
    float ds = ds_s[n*NCC + k] + EPS;
    float bs = (float)PP - ds_s[n*NCC + k] + EPS;
    float ec = de / es, dc = dd / ds, bc = (fs - dd) / bs;
    cluster[((n*NCC + k)*CC + c)*2 + 0] = ec + dc;
    cluster[((n*NCC + k)*CC + c)*2 + 1] = bc;
}

// ---- shared attn core ----
__device__ __forceinline__ void attn_weights(const float* __restrict__ fb,
                                             const float* __restrict__ cl,
                                             float4* s4) {
#pragma unroll
    for (int q = 0; q < 8; ++q) s4[q] = make_float4(0.f, 0.f, 0.f, 0.f);
#pragma unroll 4
    for (int c = 0; c < CC; ++c) {
        float4 f4 = *(const float4*)(fb + (size_t)c*PP);
#pragma unroll
        for (int k = 0; k < NCC; ++k) {
            float2 cv = *(const float2*)(cl + (k*CC + c)*2);
            s4[2*k].x   += f4.x*cv.x; s4[2*k].y   += f4.y*cv.x;
            s4[2*k].z   += f4.z*cv.x; s4[2*k].w   += f4.w*cv.x;
            s4[2*k+1].x += f4.x*cv.y; s4[2*k+1].y += f4.y*cv.y;
            s4[2*k+1].z += f4.z*cv.y; s4[2*k+1].w += f4.w*cv.y;
        }
    }
#pragma unroll
    for (int k = 0; k < NCC; ++k) {
        float4 a = s4[2*k], b = s4[2*k+1];
#define SMC(C) { float m = fmaxf(a.C, b.C); \
                 float e0 = __expf(a.C - m), e1 = __expf(b.C - m); \
                 float r = 1.f / (e0 + e1); \
                 s4[2*k].C = e0*r; s4[2*k+1].C = e1*r; }
        SMC(x) SMC(y) SMC(z) SMC(w)
#undef SMC
    }
}

// ---- K6a: attn + BN stats, register-only. Padded bn accumulators. ----
__global__ __launch_bounds__(256, 4) void k_attn_stats(const float* __restrict__ feat,
                                                       const float* __restrict__ cluster,
                                                       const float* __restrict__ kptr,
                                                       float* __restrict__ bnsum,
                                                       float* __restrict__ bnsq) {
    __shared__ float cl[NCC*CC*2];        // 256
    __shared__ float sacc[CC][2];
    const int blocks_per_n = PP / 1024;   // 864
    int b = blockIdx.x;
    int n = b / blocks_per_n;
    int p0 = (b % blocks_per_n) * 1024 + threadIdx.x * 4;
    int t = threadIdx.x;

    cl[t] = cluster[n*NCC*CC*2 + t];
    if (t < CC*2) ((float*)sacc)[t] = 0.f;
    __syncthreads();

    const float* fb = feat + (size_t)n*CC*PP + p0;
    float4 s4[8];
    attn_weights(fb, cl, s4);
    float kk = kptr[0];

#pragma unroll 4
    for (int c = 0; c < CC; ++c) {
        float4 f4 = *(const float4*)(fb + (size_t)c*PP);   // L2-hot re-read
        float4 a4 = make_float4(0.f, 0.f, 0.f, 0.f);
#pragma unroll
        for (int k = 0; k < NCC; ++k) {
            float2 cv = *(const float2*)(cl + (k*CC + c)*2);
            a4.x += s4[2*k].x*cv.x + s4[2*k+1].x*cv.y;
            a4.y += s4[2*k].y*cv.x + s4[2*k+1].y*cv.y;
            a4.z += s4[2*k].z*cv.x + s4[2*k+1].z*cv.y;
            a4.w += s4[2*k].w*cv.x + s4[2*k+1].w*cv.y;
        }
        float ox = 5.f*f4.x + kk*a4.x;
        float oy = 5.f*f4.y + kk*a4.y;
        float oz = 5.f*f4.z + kk*a4.z;
        float ow = 5.f*f4.w + kk*a4.w;
        float so = ox + oy + oz + ow;
        float sq = ox*ox + oy*oy + oz*oz + ow*ow;
        so = wave_reduce(so); sq = wave_reduce(sq);
        if ((t & 63) == 0) { atomicAdd(&sacc[c][0], so); atomicAdd(&sacc[c][1], sq); }
    }
    __syncthreads();
    if (t < CC) {
        atomicAdd(&bnsum[t*16], sacc[t][0]);
        atomicAdd(&bnsq[t*16],  sacc[t][1]);
    }
}

// ---- K8: BN finalize (padded stats in) ----
__global__ __launch_bounds__(64) void k_bnfin(const float* __restrict__ bnsum,
                                              const float* __restrict__ bnsq,
                                              const float* __restrict__ wgt,
                                              const float* __restrict__ bias,
                                              float* __restrict__ scale,
                                              float* __restrict__ shift) {
    int c = threadIdx.x;
    if (c < CC) {
        float inv_n = 1.f / (float)((size_t)NN * PP);
        float mean = bnsum[c*16] * inv_n;
        float var  = bnsq[c*16] * inv_n - mean*mean;
        float inv  = 1.f / sqrtf(var + EPS);
        float sc = wgt[c] * inv;
        scale[c] = sc;
        shift[c] = bias[c] - mean*sc;
    }
}

// ---- K6b: recompute attn, write normalized out directly. ----
__global__ __launch_bounds__(256, 4) void k_attn_write(const float* __restrict__ feat,
                                                       const float* __restrict__ cluster,
                                                       const float* __restrict__ kptr,
                                                       const float* __restrict__ scale,
                                                       const float* __restrict__ shift,
                                                       float* __restrict__ out) {
    __shared__ float cl[NCC*CC*2];        // 256
    __shared__ float scl[CC], ssh[CC];
    const int blocks_per_n = PP / 1024;   // 864
    int b = blockIdx.x;
    int n = b / blocks_per_n;
    int p0 = (b % blocks_per_n) * 1024 + threadIdx.x * 4;
    int t = threadIdx.x;

    cl[t] = cluster[n*NCC*CC*2 + t];
    if (t < CC) { scl[t] = scale[t]; ssh[t] = shift[t]; }
    __syncthreads();

    const float* fb = feat + (size_t)n*CC*PP + p0;
    float4 s4[8];
    attn_weights(fb, cl, s4);
    float kk = kptr[0];
    float* ob = out + (size_t)n*CC*PP + p0;

#pragma unroll 4
    for (int c = 0; c < CC; ++c) {
        float4 f4 = *(const float4*)(fb + (size_t)c*PP);   // L2-hot re-read
        float4 a4 = make_float4(0.f, 0.f, 0.f, 0.f);
#pragma unroll
        for (int k = 0; k < NCC; ++k) {
            float2 cv = *(const float2*)(cl + (k*CC + c)*2);
            a4.x += s4[2*k].x*cv.x + s4[2*k+1].x*cv.y;
            a4.y += s4[2*k].y*cv.x + s4[2*k+1].y*cv.y;
            a4.z += s4[2*k].z*cv.x + s4[2*k+1].z*cv.y;
            a4.w += s4[2*k].w*cv.x + s4[2*k+1].w*cv.y;
        }
        float sc = scl[c], sh = ssh[c];
        float4 o;
        o.x = (5.f*f4.x + kk*a4.x)*sc + sh;
        o.y = (5.f*f4.y + kk*a4.y)*sc + sh;
        o.z = (5.f*f4.z + kk*a4.z)*sc + sh;
        o.w = (5.f*f4.w + kk*a4.w)*sc + sh;
        *(float4*)(ob + (size_t)c*PP) = o;
    }
}

extern "C" void kernel_launch(void* const* d_in, const int* in_sizes, int n_in,
                              void* d_out, int out_size, void* d_ws, size_t ws_size,
                              hipStream_t stream) {
    const float* feat = (const float*)d_in[0];
    const float* x    = (const float*)d_in[1];
    const float* kp   = (const float*)d_in[2];
    const float* bnw  = (const float*)d_in[3];
    const float* bnb  = (const float*)d_in[4];
    float* out = (float*)d_out;
    float* ws  = (float*)d_ws;

    float* mask = ws;
    float* t0   = ws + 1*(size_t)NCP;
    float* t1   = ws + 2*(size_t)NCP;
    float* t2   = ws + 3*(size_t)NCP;
    float* dil  = ws + 4*(size_t)NCP;
    float* ero  = ws + 5*(size_t)NCP;
    float* acc  = ws + 6*(size_t)NCP;
    float* dot_e   = acc;          // 256
    float* dot_d   = acc + 256;    // 256
    float* fsum    = acc + 512;    // 64
    float* bnsum   = acc + 576;    // 512 (32 ch x 16 stride, padded)
    float* bnsq    = acc + 1088;   // 512 (padded)
    float* cluster = acc + 1600;   // 512
    float* scale   = acc + 2112;   // 32
    float* shift   = acc + 2144;   // 32
    float* epart   = acc + 2176;   // 6912
    float* dpart   = acc + 2176 + PD_BLOCKS;  // 6912

    hipMemsetAsync(acc, 0, 1600 * sizeof(float), stream);

    k_poolH     <<<NCP/1024, 256, 0, stream>>>(x, mask, t0, t1);
    k_poolW     <<<NCP/1024, 256, 0, stream>>>(t0, mask, t2, t1);
    k_poolD     <<<PD_BLOCKS, 256, 0, stream>>>(t2, mask, t1, dil, ero, epart, dpart);
    k_dots      <<<NN*4*DOT_PSPLIT, 256, 0, stream>>>(feat, ero, dil, dot_e, dot_d, fsum);
    k_cluster   <<<1, 256, 0, stream>>>(dot_e, dot_d, fsum, epart, dpart, cluster);
    k_attn_stats<<<NN*(PP/1024), 256, 0, stream>>>(feat, cluster, kp, bnsum, bnsq);
    k_bnfin     <<<1, 64, 0, stream>>>(bnsum, bnsq, bnw, bnb, scale, shift);
    k_attn_write<<<NN*(PP/1024), 256, 0, stream>>>(feat, cluster, kp, scale, shift, out);
}